// Round 2
// baseline (2175.544 us; speedup 1.0000x reference)
//
#include <hip/hip_runtime.h>
#include <cstdint>
#include <cstddef>

typedef _Float16 f16;
typedef _Float16 f16x8 __attribute__((ext_vector_type(8)));
typedef float    fx4   __attribute__((ext_vector_type(4)));

// ---------------- elementwise prep ----------------

__device__ __forceinline__ float softplus_f(float x) {
    return (x > 20.0f) ? x : log1pf(expf(x));
}

// A = mw + softplus(sw)*zw -> f16 hi plane (+ optional lo residual plane)
__global__ void prep_w_kernel(const float* __restrict__ mw, const float* __restrict__ sw,
                              const float* __restrict__ zw, f16* __restrict__ hi,
                              f16* __restrict__ lo, int n) {
    int i = (blockIdx.x * blockDim.x + threadIdx.x) * 4;
    if (i >= n) return;
    float4 m4 = *(const float4*)(mw + i);
    float4 s4 = *(const float4*)(sw + i);
    float4 z4 = *(const float4*)(zw + i);
    float a[4];
    a[0] = m4.x + softplus_f(s4.x) * z4.x;
    a[1] = m4.y + softplus_f(s4.y) * z4.y;
    a[2] = m4.z + softplus_f(s4.z) * z4.z;
    a[3] = m4.w + softplus_f(s4.w) * z4.w;
    f16 h4[4], l4[4];
#pragma unroll
    for (int j = 0; j < 4; ++j) {
        h4[j] = (f16)a[j];
        l4[j] = (f16)(a[j] - (float)h4[j]);
    }
    *(f16x8*)0; // (unused; keep types quiet)
    *(short4*)(hi + i) = *(short4*)h4;
    if (lo) *(short4*)(lo + i) = *(short4*)l4;
}

__global__ void prep_b_kernel(const float* __restrict__ mb, const float* __restrict__ sb,
                              const float* __restrict__ zb, float* __restrict__ b, int n) {
    int i = blockIdx.x * blockDim.x + threadIdx.x;
    if (i < n) b[i] = mb[i] + softplus_f(sb[i]) * zb[i];
}

// split fp32 x into f16 hi + lo planes
__global__ void split_x_kernel(const float* __restrict__ x, f16* __restrict__ hi,
                               f16* __restrict__ lo, int n) {
    int i = (blockIdx.x * blockDim.x + threadIdx.x) * 4;
    if (i >= n) return;
    float4 v = *(const float4*)(x + i);
    float a[4] = {v.x, v.y, v.z, v.w};
    f16 h4[4], l4[4];
#pragma unroll
    for (int j = 0; j < 4; ++j) {
        h4[j] = (f16)a[j];
        l4[j] = (f16)(a[j] - (float)h4[j]);
    }
    *(short4*)(hi + i) = *(short4*)h4;
    *(short4*)(lo + i) = *(short4*)l4;
}

// ---------------- GEMM: C[M,N] = H[M,K] @ W[N,K]^T (+bias, opt tanh) ----------------
// 128x128 block tile, BK=32, 4 waves, each wave 64x64 = 4x4 of 16x16x32 MFMA.
// SPLIT=1: 3-pass split-f16 (hi*hi + hi*lo + lo*hi) for ~fp32 effective precision.
// OUT: 0 = f16 hi plane (tanh), 1 = f16 hi+lo planes (tanh), 2 = fp32 (no tanh, last)

__device__ __forceinline__ void cp16(const f16* g, f16* l) {
    __builtin_amdgcn_global_load_lds((__attribute__((address_space(1))) void*)g,
                                     (__attribute__((address_space(3))) void*)l,
                                     16, 0, 0);
}

template <int SPLIT, int OUT>
__global__ __launch_bounds__(256) void gemm_kernel(
    const f16* __restrict__ Hhi, const f16* __restrict__ Hlo,
    const f16* __restrict__ Whi, const f16* __restrict__ Wlo,
    const float* __restrict__ bias,
    f16* __restrict__ Ohi, f16* __restrict__ Olo, float* __restrict__ Of,
    int M, int N, int K)
{
    constexpr int LDSN = 128 * 32;
    __shared__ __align__(16) f16 Hs[(SPLIT ? 2 : 1) * LDSN];
    __shared__ __align__(16) f16 Ws[(SPLIT ? 2 : 1) * LDSN];

    const int tid  = threadIdx.x;
    const int lane = tid & 63;
    const int wave = tid >> 6;
    const int wm   = wave >> 1;
    const int wn   = wave & 1;
    const int col  = lane & 15;
    const int quad = lane >> 4;
    const int mBase = blockIdx.y * 128;
    const int nBase = blockIdx.x * 128;

    float bias_v[4];
#pragma unroll
    for (int nt = 0; nt < 4; ++nt)
        bias_v[nt] = bias[nBase + wn * 64 + nt * 16 + col];

    fx4 acc[4][4];
#pragma unroll
    for (int i = 0; i < 4; ++i)
#pragma unroll
        for (int j = 0; j < 4; ++j)
            acc[i][j] = (fx4){0.f, 0.f, 0.f, 0.f};

    // staging: tile = 128 rows x 32 f16 = 512 chunks of 16B; chunk c -> row c>>2, colchunk c&3
    // wave w covers chunks [w*128, w*128+128) in two issues; LDS dest = uniform base + lane*16
    const int c0 = wave * 128 + lane;

    for (int k0 = 0; k0 < K; k0 += 32) {
        __syncthreads();
#pragma unroll
        for (int i = 0; i < 2; ++i) {
            int c  = c0 + i * 64;
            int r  = c >> 2;
            int cc = c & 3;
            size_t gh = (size_t)(mBase + r) * K + k0 + cc * 8;
            size_t gw = (size_t)(nBase + r) * K + k0 + cc * 8;
            cp16(Hhi + gh, &Hs[c * 8]);
            cp16(Whi + gw, &Ws[c * 8]);
            if constexpr (SPLIT) {
                cp16(Hlo + gh, &Hs[LDSN + c * 8]);
                cp16(Wlo + gw, &Ws[LDSN + c * 8]);
            }
        }
        __syncthreads();

        f16x8 bh[4], bl[4];
#pragma unroll
        for (int nt = 0; nt < 4; ++nt) {
            int off = (wn * 64 + nt * 16 + col) * 32 + quad * 8;
            bh[nt] = *(const f16x8*)&Ws[off];
            if constexpr (SPLIT) bl[nt] = *(const f16x8*)&Ws[LDSN + off];
        }
#pragma unroll
        for (int mt = 0; mt < 4; ++mt) {
            int off = (wm * 64 + mt * 16 + col) * 32 + quad * 8;
            f16x8 ah = *(const f16x8*)&Hs[off];
            f16x8 al;
            if constexpr (SPLIT) al = *(const f16x8*)&Hs[LDSN + off];
#pragma unroll
            for (int nt = 0; nt < 4; ++nt) {
                acc[mt][nt] = __builtin_amdgcn_mfma_f32_16x16x32_f16(ah, bh[nt], acc[mt][nt], 0, 0, 0);
                if constexpr (SPLIT) {
                    acc[mt][nt] = __builtin_amdgcn_mfma_f32_16x16x32_f16(ah, bl[nt], acc[mt][nt], 0, 0, 0);
                    acc[mt][nt] = __builtin_amdgcn_mfma_f32_16x16x32_f16(al, bh[nt], acc[mt][nt], 0, 0, 0);
                }
            }
        }
    }

    // epilogue: C row = quad*4 + r, col = lane&15 (m89-verified layout)
#pragma unroll
    for (int mt = 0; mt < 4; ++mt) {
#pragma unroll
        for (int nt = 0; nt < 4; ++nt) {
            int n = nBase + wn * 64 + nt * 16 + col;
#pragma unroll
            for (int r = 0; r < 4; ++r) {
                int m = mBase + wm * 64 + mt * 16 + quad * 4 + r;
                float v = acc[mt][nt][r] + bias_v[nt];
                size_t idx = (size_t)m * N + n;
                if constexpr (OUT == 2) {
                    Of[idx] = v;
                } else {
                    float t = tanhf(v);
                    f16 thi = (f16)t;
                    Ohi[idx] = thi;
                    if constexpr (OUT == 1) Olo[idx] = (f16)(t - (float)thi);
                }
            }
        }
    }
}

// ---------------- host ----------------

extern "C" void kernel_launch(void* const* d_in, const int* in_sizes, int n_in,
                              void* d_out, int out_size, void* d_ws, size_t ws_size,
                              hipStream_t stream) {
    const int BATCH = 8192;
    const int sizes[5] = {1024, 4096, 4096, 4096, 1024};

    char* ws = (char*)d_ws;
    // layout (bytes):
    //   [0 .. 33,554,432)          x_hi | x_lo   (16.78 MB each)   [dead after L0]
    //   [33,554,432 .. 50,331,648) A0_hi | A0_lo (8.39 MB each)    [dead after L0]
    //   for L1: A_hi at 0, A_lo at 33,554,432 (33.55 MB each; overwrites x/A0)
    //   for L2/L3: A_hi at 0
    //   [67,108,864  .. 134,217,728) H0_hi  (later reused as H2)
    //   [134,217,728 .. 201,326,592) H0_lo
    //   [201,326,592 .. 268,435,456) H1_hi
    //   [268,435,456 .. +16,384)     bias
    // peak = 268.45 MB (during L1)
    f16*   x_hi  = (f16*)(ws + 0);
    f16*   x_lo  = (f16*)(ws + 16777216ULL);
    f16*   A0_hi = (f16*)(ws + 33554432ULL);
    f16*   A0_lo = (f16*)(ws + 41943040ULL);
    f16*   A_hi  = (f16*)(ws + 0);
    f16*   A_lo  = (f16*)(ws + 33554432ULL);
    f16*   H0_hi = (f16*)(ws + 67108864ULL);
    f16*   H0_lo = (f16*)(ws + 134217728ULL);
    f16*   H1_hi = (f16*)(ws + 201326592ULL);
    f16*   H2_hi = (f16*)(ws + 67108864ULL);   // alias H0_hi (free after L1)
    float* bb    = (float*)(ws + 268435456ULL);

    const float* x = (const float*)d_in[0];
    const float* p[4][6];
    for (int j = 0; j < 4; ++j)
        for (int t = 0; t < 6; ++t)
            p[j][t] = (const float*)d_in[1 + j * 6 + t];

    // x -> f16 hi/lo
    {
        int n = BATCH * sizes[0];
        split_x_kernel<<<n / 4 / 256, 256, 0, stream>>>(x, x_hi, x_lo, n);
    }

    // ---- layer 0: [8192,1024] @ [4096,1024]^T, 3-pass split, out hi+lo ----
    {
        int n = sizes[1] * sizes[0];
        prep_w_kernel<<<n / 4 / 256, 256, 0, stream>>>(p[0][0], p[0][1], p[0][2], A0_hi, A0_lo, n);
        prep_b_kernel<<<(sizes[1] + 255) / 256, 256, 0, stream>>>(p[0][3], p[0][4], p[0][5], bb, sizes[1]);
        dim3 grid(sizes[1] / 128, BATCH / 128);
        gemm_kernel<1, 1><<<grid, 256, 0, stream>>>(
            x_hi, x_lo, A0_hi, A0_lo, bb, H0_hi, H0_lo, nullptr, BATCH, sizes[1], sizes[0]);
    }

    // ---- layer 1: [8192,4096] @ [4096,4096]^T, 3-pass split, out hi ----
    {
        int n = sizes[2] * sizes[1];
        prep_w_kernel<<<n / 4 / 256, 256, 0, stream>>>(p[1][0], p[1][1], p[1][2], A_hi, A_lo, n);
        prep_b_kernel<<<(sizes[2] + 255) / 256, 256, 0, stream>>>(p[1][3], p[1][4], p[1][5], bb, sizes[2]);
        dim3 grid(sizes[2] / 128, BATCH / 128);
        gemm_kernel<1, 0><<<grid, 256, 0, stream>>>(
            H0_hi, H0_lo, A_hi, A_lo, bb, H1_hi, nullptr, nullptr, BATCH, sizes[2], sizes[1]);
    }

    // ---- layer 2: [8192,4096] @ [4096,4096]^T, single pass, out hi ----
    {
        int n = sizes[3] * sizes[2];
        prep_w_kernel<<<n / 4 / 256, 256, 0, stream>>>(p[2][0], p[2][1], p[2][2], A_hi, nullptr, n);
        prep_b_kernel<<<(sizes[3] + 255) / 256, 256, 0, stream>>>(p[2][3], p[2][4], p[2][5], bb, sizes[3]);
        dim3 grid(sizes[3] / 128, BATCH / 128);
        gemm_kernel<0, 0><<<grid, 256, 0, stream>>>(
            H1_hi, nullptr, A_hi, nullptr, bb, H2_hi, nullptr, nullptr, BATCH, sizes[3], sizes[2]);
    }

    // ---- layer 3: [8192,4096] @ [1024,4096]^T, single pass, fp32 out, no tanh ----
    {
        int n = sizes[4] * sizes[3];
        prep_w_kernel<<<n / 4 / 256, 256, 0, stream>>>(p[3][0], p[3][1], p[3][2], A_hi, nullptr, n);
        prep_b_kernel<<<(sizes[4] + 255) / 256, 256, 0, stream>>>(p[3][3], p[3][4], p[3][5], bb, sizes[4]);
        dim3 grid(sizes[4] / 128, BATCH / 128);
        gemm_kernel<0, 2><<<grid, 256, 0, stream>>>(
            H2_hi, nullptr, A_hi, nullptr, bb, nullptr, nullptr, (float*)d_out, BATCH, sizes[4], sizes[3]);
    }
}